// Round 6
// baseline (454.282 us; speedup 1.0000x reference)
//
#include <hip/hip_runtime.h>

// Problem constants (fixed by setup_inputs)
constexpr int NB = 4;
constexpr int NI = 512;
constexpr int NK = 512;
constexpr int NC = 64;
constexpr float LN_EPS = 1e-5f;

// Round-5 finding: pure linear grid-stride read of z = ~7 TB/s; structured
// readers were at 1.6-3.5 TB/s. Determinant = density of the grid's
// INSTANTANEOUS footprint. Both streamers below sweep z as dense marching
// fronts (interleaved i-assignment) with per-wave 1KB contiguous loads.

constexpr int SBLK = 64;                 // i-parallel blocks per batch in k_S
constexpr int SLAB = NK * NC;            // floats per (k,c) slab = 32768
constexpr int NSLAB = NB * SBLK;         // 256 Spart slabs (32 MB)

// ---------------------------------------------------------------------------
// k_S: Spart[blk][k,c] = sum_{i in block's set} exp(z[b,i,k,c])*(zm+1e-6)
// grid = NB*SBLK = 256 blocks x 512 threads. Block (b,ic) handles
// i = ii*64+ic (interleaved -> 64 blocks/batch march as one dense 8MB front).
// Thread's (k,c) fixed per step s: k = s*32+(tid>>4), c-quad = tid&15.
// acc[16] float4 in registers (statically indexed). Dense loads, exact mask
// weight (m+1e-6) -> matches reference exactly (incl. masked 1e-6 terms).
// ---------------------------------------------------------------------------
__global__ __launch_bounds__(512) void k_S(const float* __restrict__ z,
                                           const float* __restrict__ zmask,
                                           float* __restrict__ Spart) {
    int blk = blockIdx.x;
    int b = blk >> 6;               // / SBLK
    int ic = blk & (SBLK - 1);
    int tid = threadIdx.x;          // 0..511
    int kg = tid >> 4;              // 0..31 (k subgroup)

    __shared__ float mlds[NK];

    float4 acc[16];
#pragma unroll
    for (int s = 0; s < 16; ++s) acc[s] = make_float4(0.f, 0.f, 0.f, 0.f);

    for (int ii = 0; ii < NI / SBLK; ++ii) {
        int i = ii * SBLK + ic;     // interleaved: dense front across blocks
        const float* zs = z + (size_t)(b * NI + i) * SLAB;
        const float* mp = zmask + (size_t)(b * NI + i) * NK;
        __syncthreads();            // protect mlds from prev iteration readers
        mlds[tid] = mp[tid];        // NK == blockDim.x == 512
        __syncthreads();
#pragma unroll
        for (int s = 0; s < 16; ++s) {
            const float4 zv = *(const float4*)(zs + (size_t)(s * 512 + tid) * 4);
            float w = mlds[s * 32 + kg] + 1e-6f;
            acc[s].x += __expf(zv.x) * w;
            acc[s].y += __expf(zv.y) * w;
            acc[s].z += __expf(zv.z) * w;
            acc[s].w += __expf(zv.w) * w;
        }
    }
    float* sp = Spart + (size_t)blk * SLAB;
#pragma unroll
    for (int s = 0; s < 16; ++s)
        *(float4*)(sp + (size_t)(s * 512 + tid) * 4) = acc[s];
}

// ---------------------------------------------------------------------------
// k_R: R[b,k,c] = (dot(Q[b,k,:], W1[c,:]) + b1[c]) / sum_j Spart[b*64+j][k,c]
// grid = NB*NK blocks of 64 threads (one per c). Reads 32MB Spart.
// ---------------------------------------------------------------------------
__global__ __launch_bounds__(64) void k_R(const float* __restrict__ Q,
                                          const float* __restrict__ W1,
                                          const float* __restrict__ b1,
                                          const float* __restrict__ Spart,
                                          float* __restrict__ R) {
    int bk = blockIdx.x;            // b*NK + k
    int b = bk >> 9;
    int k = bk & (NK - 1);
    int c = threadIdx.x;
    __shared__ float q[NC];
    q[c] = Q[(size_t)bk * NC + c];
    __syncthreads();
    const float* w = W1 + c * NC;
    float acc = b1[c];
#pragma unroll
    for (int j = 0; j < NC; ++j) acc += q[j] * w[j];
    float s = 0.f;
#pragma unroll 8
    for (int j = 0; j < SBLK; ++j)
        s += Spart[(size_t)((b << 6) + j) * SLAB + (size_t)k * NC + c];
    R[(size_t)bk * NC + c] = acc / s;
}

// ---------------------------------------------------------------------------
// k_Va: Va[b,i,c] = sum_k exp(z[b,i,k,c]) * zm*(zm+1e-6) * R[b,k,c]
// grid = NB*128 blocks x 512 threads; block (b,ic) handles i = ii*128+ic
// (dense 16MB front per batch). Per i: dense 16-step sweep, thread sums its
// 16 k's into one float4 (c-quad = tid&15); R read at IDENTICAL flat offsets
// as z (L2-hot). Tail: shfl_xor(16,32) + 2KB LDS reduce. Exact math.
// Also emits per-(b,i) (sum, sumsq) for LN1.
// ---------------------------------------------------------------------------
__global__ __launch_bounds__(512) void k_Va(const float* __restrict__ z,
                                            const float* __restrict__ zmask,
                                            const float* __restrict__ R,
                                            float* __restrict__ Va,
                                            float* __restrict__ part1) {
    int blk = blockIdx.x;
    int b = blk >> 7;               // / 128
    int ic = blk & 127;
    int tid = threadIdx.x;          // 0..511
    int wave = tid >> 6;            // 0..7
    int lane = tid & 63;
    int kg = tid >> 4;              // 0..31

    __shared__ float m2lds[NK];
    __shared__ float4 wpart[8 * 16];

    const float* Rb = R + (size_t)b * SLAB;

    for (int ii = 0; ii < 4; ++ii) {
        int i = ii * 128 + ic;      // interleaved: dense front across blocks
        int bi = b * NI + i;
        const float* zs = z + (size_t)bi * SLAB;
        const float* mp = zmask + (size_t)bi * NK;
        __syncthreads();            // protect m2lds/wpart from prev readers
        {
            float m = mp[tid];
            m2lds[tid] = m * (m + 1e-6f);
        }
        __syncthreads();

        float4 a = make_float4(0.f, 0.f, 0.f, 0.f);
#pragma unroll
        for (int s = 0; s < 16; ++s) {
            const float4 zv = *(const float4*)(zs + (size_t)(s * 512 + tid) * 4);
            const float4 rv = *(const float4*)(Rb + (size_t)(s * 512 + tid) * 4);
            float w = m2lds[s * 32 + kg];
            a.x += __expf(zv.x) * w * rv.x;
            a.y += __expf(zv.y) * w * rv.y;
            a.z += __expf(zv.z) * w * rv.z;
            a.w += __expf(zv.w) * w * rv.w;
        }
        // in-wave reduce across the 4 k-subgroups (lanes ^16, ^32)
        a.x += __shfl_xor(a.x, 16); a.y += __shfl_xor(a.y, 16);
        a.z += __shfl_xor(a.z, 16); a.w += __shfl_xor(a.w, 16);
        a.x += __shfl_xor(a.x, 32); a.y += __shfl_xor(a.y, 32);
        a.z += __shfl_xor(a.z, 32); a.w += __shfl_xor(a.w, 32);
        if (lane < 16) wpart[wave * 16 + lane] = a;
        __syncthreads();
        if (tid < 16) {
            float4 f = wpart[tid];
#pragma unroll
            for (int w = 1; w < 8; ++w) {
                float4 o = wpart[w * 16 + tid];
                f.x += o.x; f.y += o.y; f.z += o.z; f.w += o.w;
            }
            *(float4*)(Va + (size_t)bi * NC + tid * 4) = f;
            float s0 = f.x + f.y + f.z + f.w;
            float s1 = f.x * f.x + f.y * f.y + f.z * f.z + f.w * f.w;
#pragma unroll
            for (int off = 1; off < 16; off <<= 1) {
                s0 += __shfl_xor(s0, off);
                s1 += __shfl_xor(s1, off);
            }
            if (tid == 0) {
                part1[bi * 2]     = s0;
                part1[bi * 2 + 1] = s1;
            }
        }
    }
}

// ---------------------------------------------------------------------------
// k_red: per-batch reduce of (sum, sumsq) partials -> stats[b*2], stats[b*2+1]
// grid = B, block = 256
// ---------------------------------------------------------------------------
__global__ __launch_bounds__(256) void k_red(const float* __restrict__ part,
                                             float* __restrict__ stats) {
    int b = blockIdx.x;
    int tid = threadIdx.x;
    float s0 = 0.f, s1 = 0.f;
    for (int i = tid; i < NI; i += 256) {
        int bi = b * NI + i;
        s0 += part[bi * 2];
        s1 += part[bi * 2 + 1];
    }
    __shared__ float l0[256], l1[256];
    l0[tid] = s0; l1[tid] = s1;
    __syncthreads();
    for (int s = 128; s; s >>= 1) {
        if (tid < s) { l0[tid] += l0[tid + s]; l1[tid] += l1[tid + s]; }
        __syncthreads();
    }
    if (tid == 0) { stats[b * 2] = l0[0]; stats[b * 2 + 1] = l1[0]; }
}

// ---------------------------------------------------------------------------
// k_Y: Y[b,i,c] = V + (LN1(Va) @ W2^T + b2); emits LN2 partials per (b,i)
// grid = B*I, block = 64 (one wave)
// ---------------------------------------------------------------------------
__global__ __launch_bounds__(64) void k_Y(const float* __restrict__ V,
                                          const float* __restrict__ W2,
                                          const float* __restrict__ b2,
                                          const float* __restrict__ Va,
                                          const float* __restrict__ stats1,
                                          float* __restrict__ Y,
                                          float* __restrict__ part2) {
    int bi = blockIdx.x;
    int b = bi >> 9;
    int c = threadIdx.x;
    const float n = (float)(NI * NC);
    float mu = stats1[b * 2] / n;
    float var = stats1[b * 2 + 1] / n - mu * mu;
    float rstd = rsqrtf(var + LN_EPS);

    __shared__ float xn[NC];
    xn[c] = (Va[(size_t)bi * NC + c] - mu) * rstd;
    __syncthreads();

    const float* w = W2 + c * NC;
    float acc = b2[c];
#pragma unroll
    for (int j = 0; j < NC; ++j) acc += xn[j] * w[j];
    float y = V[(size_t)bi * NC + c] + acc;
    Y[(size_t)bi * NC + c] = y;

    float s0 = y, s1 = y * y;
    for (int off = 32; off; off >>= 1) {
        s0 += __shfl_down(s0, off);
        s1 += __shfl_down(s1, off);
    }
    if (c == 0) { part2[bi * 2] = s0; part2[bi * 2 + 1] = s1; }
}

// ---------------------------------------------------------------------------
// k_out: out = LN2(Y), elementwise with per-b stats
// ---------------------------------------------------------------------------
__global__ __launch_bounds__(256) void k_out(const float* __restrict__ Y,
                                             const float* __restrict__ stats2,
                                             float* __restrict__ out) {
    int idx = blockIdx.x * 256 + threadIdx.x;
    int b = idx >> 15;               // / (NI*NC)
    const float n = (float)(NI * NC);
    float mu = stats2[b * 2] / n;
    float var = stats2[b * 2 + 1] / n - mu * mu;
    float rstd = rsqrtf(var + LN_EPS);
    out[idx] = (Y[idx] - mu) * rstd;
}

// ---------------------------------------------------------------------------
extern "C" void kernel_launch(void* const* d_in, const int* in_sizes, int n_in,
                              void* d_out, int out_size, void* d_ws, size_t ws_size,
                              hipStream_t stream) {
    const float* V  = (const float*)d_in[0];
    const float* Q  = (const float*)d_in[1];
    const float* z  = (const float*)d_in[2];
    const float* zm = (const float*)d_in[3];
    const float* W1 = (const float*)d_in[4];
    const float* b1 = (const float*)d_in[5];
    const float* W2 = (const float*)d_in[6];
    const float* b2 = (const float*)d_in[7];
    // d_in[8] is dim == 1 (fixed by setup_inputs)

    float* ws     = (float*)d_ws;
    float* Spart  = ws;                          // NSLAB*SLAB = 8,388,608 floats (32 MB)
    float* R      = ws + 8388608;                // 131072
    float* Va     = ws + 8519680;                // 131072
    float* Y      = ws + 8650752;                // 131072
    float* part1  = ws + 8781824;                // 4096
    float* part2  = ws + 8785920;                // 4096
    float* stats1 = ws + 8790016;                // 8
    float* stats2 = ws + 8790024;                // 8

    k_S  <<<NSLAB,               512, 0, stream>>>(z, zm, Spart);
    k_R  <<<NB * NK,             64,  0, stream>>>(Q, W1, b1, Spart, R);
    k_Va <<<NB * 128,            512, 0, stream>>>(z, zm, R, Va, part1);
    k_red<<<NB,                  256, 0, stream>>>(part1, stats1);
    k_Y  <<<NB * NI,             64,  0, stream>>>(V, W2, b2, Va, stats1, Y, part2);
    k_red<<<NB,                  256, 0, stream>>>(part2, stats2);
    k_out<<<(NB * NI * NC) / 256, 256, 0, stream>>>(Y, stats2, (float*)d_out);
}